// Round 1
// baseline (118.240 us; speedup 1.0000x reference)
//
#include <hip/hip_runtime.h>

// Problem constants
#define BATCH 64
#define GH 14
#define GW 14
#define NPATCH (GH*GW)        // 196
#define M_ROWS (BATCH*NPATCH) // 12544
#define KDIM 768              // 3*16*16
#define DDIM 384              // EMBED
#define HW (224*224)

typedef __attribute__((ext_vector_type(8))) short s16x8;
typedef __attribute__((ext_vector_type(4))) float f32x4;
typedef __attribute__((ext_vector_type(4))) unsigned short u16x4;

__device__ __forceinline__ unsigned short f2bf(float f) {
    unsigned int u = __float_as_uint(f);
    u += 0x7fff + ((u >> 16) & 1);   // round-to-nearest-even
    return (unsigned short)(u >> 16);
}

__device__ __forceinline__ s16x8 cvt8(float4 lo, float4 hi) {
    s16x8 o;
    o[0] = (short)f2bf(lo.x); o[1] = (short)f2bf(lo.y);
    o[2] = (short)f2bf(lo.z); o[3] = (short)f2bf(lo.w);
    o[4] = (short)f2bf(hi.x); o[5] = (short)f2bf(hi.y);
    o[6] = (short)f2bf(hi.z); o[7] = (short)f2bf(hi.w);
    return o;
}

// ---------------- kernel 1: weight fp32 -> bf16 cast (B^T, row-major 384x768) --
__global__ __launch_bounds__(256) void wcast_kernel(const float* __restrict__ w,
                                                    unsigned short* __restrict__ W) {
    int t = blockIdx.x * 256 + threadIdx.x;   // 73728 float4s total
    float4 v = ((const float4*)w)[t];
    u16x4 o = { f2bf(v.x), f2bf(v.y), f2bf(v.z), f2bf(v.w) };
    *(u16x4*)(W + t * 4) = o;
}

// ---------------- kernel 2: fused im2col + entropy + GEMM + bias + LayerNorm --
// 196 blocks x 384 threads (6 waves). Block owns 64 consecutive patch rows.
// A is built per K-tile straight from image pixels (fp32 L2-warm after the
// entropy pass) -> bf16 regs -> swizzled ds_write. B reg-staged with
// issue-early / write-late pipeline so L2 latency hides under MFMA.
// LDS slot formula identical to the verified kernel: slot kss holds global
// chunk kss^(row&7); fragment read uses sw = (ks*4+quad)^(cl&7).
__global__ __launch_bounds__(384) void fused_kernel(const float* __restrict__ img,
                                                    const unsigned short* __restrict__ Bt,
                                                    const float* __restrict__ bias,
                                                    const float* __restrict__ gamma,
                                                    const float* __restrict__ beta,
                                                    float* __restrict__ C,
                                                    float* __restrict__ ent) {
    __shared__ __align__(16) unsigned short As[64 * 64];    //  8 KB (one K-tile)
    __shared__ __align__(16) unsigned short Bs[384 * 64];   // 48 KB (one K-tile)
    __shared__ int hist[6][32];
    __shared__ float sred[64], sred2[64], smean[64], srstd[64];

    const int tid  = threadIdx.x;
    const int lane = tid & 63;
    const int wv   = tid >> 6;                // wave 0..5
    const int quad = lane >> 4;
    const int cl   = lane & 15;
    const int rowBase = blockIdx.x * 64;

    if (tid < 64) { sred[tid] = 0.0f; sred2[tid] = 0.0f; }

    // ---- per-thread A-staging constants (chunk ownership is static) ----
    // chunk c=tid -> row r1=tid>>3, K-subchunk ksg=tid&7; second chunk (tid<128)
    // covers rows 48..63. K = ch*256 + prow*16 + col; chunk -> ch=kt>>2,
    // prow=(kt&3)*4+(ksg>>1), col=(ksg&1)*8.
    const int r1  = tid >> 3, ksg = tid & 7;
    const int sA1 = r1 * 64 + (ksg ^ (r1 & 7)) * 8;
    const int r2  = r1 + 48;
    const int sA2 = r2 * 64 + (ksg ^ (r2 & 7)) * 8;
    const float *pA1, *pA2;
    {
        int p = rowBase + r1, b = p / NPATCH, n = p - b * NPATCH;
        int ph = n / GW, pw_ = n - ph * GW;
        pA1 = img + (size_t)b * (3 * HW) + (ph * 16 + (ksg >> 1)) * 224 + pw_ * 16 + (ksg & 1) * 8;
        p = rowBase + r2; b = p / NPATCH; n = p - b * NPATCH;       // pointer only
        ph = n / GW; pw_ = n - ph * GW;                              // deref'd iff tid<128
        pA2 = img + (size_t)b * (3 * HW) + (ph * 16 + (ksg >> 1)) * 224 + pw_ * 16 + (ksg & 1) * 8;
    }
    // ---- B-staging constants: chunk c=i*384+tid -> row n=i*48+(tid>>3),
    // K-subchunk tid&7; write slot (tid&7)^(n&7) with n&7=(tid>>3)&7.
    const unsigned short* pB0 = Bt + (size_t)(tid >> 3) * KDIM + (tid & 7) * 8;
    const int sB = (tid >> 3) * 64 + ((tid & 7) ^ ((tid >> 3) & 7)) * 8;

    // ---- prologue: issue tile-0 loads (fly during the entropy phase) ----
    s16x8 breg[8];
#pragma unroll
    for (int i = 0; i < 8; ++i)
        breg[i] = *(const s16x8*)(pB0 + (size_t)i * (48 * KDIM));
    float4 a1lo = *(const float4*)(pA1);
    float4 a1hi = *(const float4*)(pA1 + 4);
    float4 a2lo, a2hi;
    if (tid < 128) { a2lo = *(const float4*)(pA2); a2hi = *(const float4*)(pA2 + 4); }

    // ---- phase 1: patch entropy (wave-per-patch, 2-deep pixel prefetch) ----
    {
        const int pr  = lane >> 2;            // pixel row 0..15
        const int cc4 = (lane & 3) * 4;       // pixel col 0,4,8,12
        int p0 = rowBase + wv, b0 = p0 / NPATCH, n0i = p0 - b0 * NPATCH;
        int ph0 = n0i / GW, pw0 = n0i - ph0 * GW;
        const float* bp = img + (size_t)b0 * (3 * HW) + (ph0 * 16 + pr) * 224 + pw0 * 16 + cc4;
        float4 c0 = *(const float4*)(bp);
        float4 c1 = *(const float4*)(bp + HW);
        float4 c2 = *(const float4*)(bp + 2 * HW);
        for (int pp = wv; pp < 64; pp += 6) {
            float4 n0, n1, n2;
            if (pp + 6 < 64) {
                int p = rowBase + pp + 6, b = p / NPATCH, n = p - b * NPATCH;
                int ph = n / GW, pw_ = n - ph * GW;
                const float* np = img + (size_t)b * (3 * HW) + (ph * 16 + pr) * 224 + pw_ * 16 + cc4;
                n0 = *(const float4*)(np);
                n1 = *(const float4*)(np + HW);
                n2 = *(const float4*)(np + 2 * HW);
            }
            if (lane < 32) hist[wv][lane] = 0;
            asm volatile("s_waitcnt lgkmcnt(0)" ::: "memory");   // zero visible wave-wide
            float g[4] = { (c0.x + c1.x + c2.x) / 3.0f, (c0.y + c1.y + c2.y) / 3.0f,
                           (c0.z + c1.z + c2.z) / 3.0f, (c0.w + c1.w + c2.w) / 3.0f };
#pragma unroll
            for (int j = 0; j < 4; ++j) {
                int bin = (int)(g[j] * 31.0f);
                bin = bin < 0 ? 0 : (bin > 31 ? 31 : bin);
                atomicAdd(&hist[wv][bin], 1);
            }
            asm volatile("s_waitcnt lgkmcnt(0)" ::: "memory");   // atomics done
            float t = 0.0f;
            if (lane < 32) {
                float prb = (float)hist[wv][lane] * (1.0f / 256.0f);
                t = -prb * log2f(prb + 1e-10f);
            }
#pragma unroll
            for (int off = 32; off; off >>= 1) t += __shfl_xor(t, off);
            if (lane == 0) ent[rowBase + pp] = t * (1.0f / 5.0f);  // / log2(32)
            c0 = n0; c1 = n1; c2 = n2;
        }
    }

    // ---- stage tile 0 into LDS (prologue loads have landed by now) ----
    *(s16x8*)(As + sA1) = cvt8(a1lo, a1hi);
    if (tid < 128) *(s16x8*)(As + sA2) = cvt8(a2lo, a2hi);
#pragma unroll
    for (int i = 0; i < 8; ++i)
        *(s16x8*)(Bs + sB + i * (48 * 64)) = breg[i];
    __syncthreads();

    // ---- main K-loop: issue loads(kt+1) -> MFMA(kt) -> barrier -> ds_write ----
    f32x4 acc[4][4] = {};
    for (int kt = 0; kt < 12; ++kt) {
        if (kt < 11) {
            const int kn = kt + 1;
            const float* pa = pA1 + (kn >> 2) * HW + (kn & 3) * (4 * 224);
            a1lo = *(const float4*)(pa);
            a1hi = *(const float4*)(pa + 4);
            if (tid < 128) {
                const float* pa2 = pA2 + (kn >> 2) * HW + (kn & 3) * (4 * 224);
                a2lo = *(const float4*)(pa2);
                a2hi = *(const float4*)(pa2 + 4);
            }
#pragma unroll
            for (int i = 0; i < 8; ++i)
                breg[i] = *(const s16x8*)(pB0 + (size_t)i * (48 * KDIM) + kn * 64);
        }
#pragma unroll
        for (int ks = 0; ks < 2; ++ks) {
            const int sw = (ks * 4 + quad) ^ (cl & 7);
            s16x8 a_frag[4], b_frag[4];
#pragma unroll
            for (int i = 0; i < 4; ++i) {
                a_frag[i] = *(const s16x8*)(As + (i * 16 + cl) * 64 + sw * 8);
                b_frag[i] = *(const s16x8*)(Bs + (wv * 64 + i * 16 + cl) * 64 + sw * 8);
            }
#pragma unroll
            for (int i = 0; i < 4; ++i)
#pragma unroll
                for (int j = 0; j < 4; ++j)
                    acc[i][j] = __builtin_amdgcn_mfma_f32_16x16x32_bf16(
                        a_frag[i], b_frag[j], acc[i][j], 0, 0, 0);
        }
        __syncthreads();                       // all waves done reading tile kt
        if (kt < 11) {
            *(s16x8*)(As + sA1) = cvt8(a1lo, a1hi);
            if (tid < 128) *(s16x8*)(As + sA2) = cvt8(a2lo, a2hi);
#pragma unroll
            for (int i = 0; i < 8; ++i)
                *(s16x8*)(Bs + sB + i * (48 * 64)) = breg[i];
        }
        __syncthreads();                       // tile kt+1 ready
    }

    // ---- epilogue: bias + LayerNorm(384) + write (verified code) ----
    float bv[4], gv[4], btv[4];
#pragma unroll
    for (int j = 0; j < 4; ++j) {
        int col = wv * 64 + j * 16 + cl;
        bv[j] = bias[col]; gv[j] = gamma[col]; btv[j] = beta[col];
    }

#pragma unroll
    for (int i = 0; i < 4; ++i) {
#pragma unroll
        for (int r = 0; r < 4; ++r) {
            float s1 = 0.0f, s2 = 0.0f;
#pragma unroll
            for (int j = 0; j < 4; ++j) {
                float v = acc[i][j][r] + bv[j];
                s1 += v; s2 += v * v;
            }
#pragma unroll
            for (int off = 1; off < 16; off <<= 1) {
                s1 += __shfl_xor(s1, off);
                s2 += __shfl_xor(s2, off);
            }
            if (cl == 0) {
                int row = i * 16 + quad * 4 + r;
                atomicAdd(&sred[row], s1);
                atomicAdd(&sred2[row], s2);
            }
        }
    }
    __syncthreads();
    if (tid < 64) {
        float mu  = sred[tid] * (1.0f / (float)DDIM);
        float var = sred2[tid] * (1.0f / (float)DDIM) - mu * mu;
        smean[tid] = mu;
        srstd[tid] = rsqrtf(var + 1e-5f);
    }
    __syncthreads();

#pragma unroll
    for (int i = 0; i < 4; ++i) {
#pragma unroll
        for (int r = 0; r < 4; ++r) {
            int row = i * 16 + quad * 4 + r;
            float mu = smean[row], rs = srstd[row];
            float* crow = C + (size_t)(rowBase + row) * DDIM;
#pragma unroll
            for (int j = 0; j < 4; ++j)
                crow[wv * 64 + j * 16 + cl] = (acc[i][j][r] + bv[j] - mu) * rs * gv[j] + btv[j];
        }
    }
}

extern "C" void kernel_launch(void* const* d_in, const int* in_sizes, int n_in,
                              void* d_out, int out_size, void* d_ws, size_t ws_size,
                              hipStream_t stream) {
    const float* img = (const float*)d_in[0];
    const float* pw  = (const float*)d_in[1];
    const float* pb  = (const float*)d_in[2];
    const float* gam = (const float*)d_in[3];
    const float* bet = (const float*)d_in[4];
    float* out = (float*)d_out;

    unsigned short* Wbf = (unsigned short*)d_ws;          // 384*768*2 = 589824 B
    float* ent = out + (size_t)M_ROWS * DDIM;             // entropy after x

    hipLaunchKernelGGL(wcast_kernel, dim3(288), dim3(256), 0, stream, pw, Wbf);
    hipLaunchKernelGGL(fused_kernel, dim3(196), dim3(384), 0, stream,
                       img, Wbf, pb, gam, bet, out, ent);
}

// Round 2
// 113.702 us; speedup vs baseline: 1.0399x; 1.0399x over previous
//
#include <hip/hip_runtime.h>

// Problem constants
#define BATCH 64
#define GH 14
#define GW 14
#define NPATCH (GH*GW)        // 196
#define M_ROWS (BATCH*NPATCH) // 12544
#define KDIM 768              // 3*16*16
#define DDIM 384              // EMBED
#define HW (224*224)

typedef __attribute__((ext_vector_type(8))) short s16x8;
typedef __attribute__((ext_vector_type(4))) float f32x4;
typedef __attribute__((ext_vector_type(4))) unsigned short u16x4;

__device__ __forceinline__ unsigned short f2bf(float f) {
    unsigned int u = __float_as_uint(f);
    u += 0x7fff + ((u >> 16) & 1);   // round-to-nearest-even
    return (unsigned short)(u >> 16);
}

__device__ __forceinline__ s16x8 cvt8(float4 lo, float4 hi) {
    s16x8 o;
    o[0] = (short)f2bf(lo.x); o[1] = (short)f2bf(lo.y);
    o[2] = (short)f2bf(lo.z); o[3] = (short)f2bf(lo.w);
    o[4] = (short)f2bf(hi.x); o[5] = (short)f2bf(hi.y);
    o[6] = (short)f2bf(hi.z); o[7] = (short)f2bf(hi.w);
    return o;
}

// ---------------- kernel 1: weight fp32 -> bf16 cast (B^T, row-major 384x768) --
__global__ __launch_bounds__(256) void wcast_kernel(const float* __restrict__ w,
                                                    unsigned short* __restrict__ W) {
    int t = blockIdx.x * 256 + threadIdx.x;   // 73728 float4s total
    float4 v = ((const float4*)w)[t];
    u16x4 o = { f2bf(v.x), f2bf(v.y), f2bf(v.z), f2bf(v.w) };
    *(u16x4*)(W + t * 4) = o;
}

// ---------------- kernel 2: fused im2col + entropy + GEMM + bias + LayerNorm --
// 392 blocks x 384 threads (6 waves). Block owns 32 consecutive patch rows
// (full N=384 per block -- required by the fused LayerNorm reduction).
// ~53 KB LDS -> 2 blocks/CU co-resident so K-loop barriers and the entropy
// phase of one block hide under the MFMA phase of the other.
// A is built per K-tile straight from image pixels (fp32, L2/L3-warm after
// the entropy pass) -> bf16 regs -> swizzled ds_write. B reg-staged with
// issue-early / write-late so L2 latency hides under MFMA.
// LDS slot formula identical to the verified kernel: slot kss holds global
// chunk kss^(row&7); fragment read uses sw = (ks*4+quad)^(cl&7).
__global__ __launch_bounds__(384) void fused_kernel(const float* __restrict__ img,
                                                    const unsigned short* __restrict__ Bt,
                                                    const float* __restrict__ bias,
                                                    const float* __restrict__ gamma,
                                                    const float* __restrict__ beta,
                                                    float* __restrict__ C,
                                                    float* __restrict__ ent) {
    __shared__ __align__(16) unsigned short As[32 * 64];    //  4 KB (one K-tile)
    __shared__ __align__(16) unsigned short Bs[384 * 64];   // 48 KB (one K-tile)
    __shared__ int hist[6][32];
    __shared__ float sred[32], sred2[32], smean[32], srstd[32];

    const int tid  = threadIdx.x;
    const int lane = tid & 63;
    const int wv   = tid >> 6;                // wave 0..5
    const int quad = lane >> 4;
    const int cl   = lane & 15;
    const int rowBase = blockIdx.x * 32;

    if (tid < 32) { sred[tid] = 0.0f; sred2[tid] = 0.0f; }

    // ---- per-thread A-staging constants (threads 0..255 own one chunk) ----
    // chunk c=tid -> row r1=tid>>3 (0..31), K-subchunk ksg=tid&7.
    // K = ch*256 + prow*16 + col; per K-tile kt: ch=kt>>2, prow=(kt&3)*4+(ksg>>1),
    // col=(ksg&1)*8.
    const int r1  = tid >> 3, ksg = tid & 7;
    const int sA1 = r1 * 64 + (ksg ^ (r1 & 7)) * 8;
    const float* pA1;
    {
        int p = rowBase + r1, b = p / NPATCH, n = p - b * NPATCH;
        int ph = n / GW, pw_ = n - ph * GW;
        pA1 = img + (size_t)b * (3 * HW) + (ph * 16 + (ksg >> 1)) * 224 + pw_ * 16 + (ksg & 1) * 8;
    }
    // ---- B-staging constants: chunk c=i*384+tid -> row n=i*48+(tid>>3),
    // K-subchunk tid&7; write slot (tid&7)^(n&7) with n&7=(tid>>3)&7.
    const unsigned short* pB0 = Bt + (size_t)(tid >> 3) * KDIM + (tid & 7) * 8;
    const int sB = (tid >> 3) * 64 + ((tid & 7) ^ ((tid >> 3) & 7)) * 8;

    // ---- prologue: issue tile-0 loads (fly during the entropy phase) ----
    s16x8 breg[8];
#pragma unroll
    for (int i = 0; i < 8; ++i)
        breg[i] = *(const s16x8*)(pB0 + (size_t)i * (48 * KDIM));
    float4 a1lo, a1hi;
    if (tid < 256) {
        a1lo = *(const float4*)(pA1);
        a1hi = *(const float4*)(pA1 + 4);
    }

    // ---- phase 1: patch entropy (wave-per-patch, 1-deep pixel prefetch) ----
    {
        const int pr  = lane >> 2;            // pixel row 0..15
        const int cc4 = (lane & 3) * 4;       // pixel col 0,4,8,12
        int p0 = rowBase + wv, b0 = p0 / NPATCH, n0i = p0 - b0 * NPATCH;
        int ph0 = n0i / GW, pw0 = n0i - ph0 * GW;
        const float* bp = img + (size_t)b0 * (3 * HW) + (ph0 * 16 + pr) * 224 + pw0 * 16 + cc4;
        float4 c0 = *(const float4*)(bp);
        float4 c1 = *(const float4*)(bp + HW);
        float4 c2 = *(const float4*)(bp + 2 * HW);
        for (int pp = wv; pp < 32; pp += 6) {
            float4 n0, n1, n2;
            if (pp + 6 < 32) {
                int p = rowBase + pp + 6, b = p / NPATCH, n = p - b * NPATCH;
                int ph = n / GW, pw_ = n - ph * GW;
                const float* np = img + (size_t)b * (3 * HW) + (ph * 16 + pr) * 224 + pw_ * 16 + cc4;
                n0 = *(const float4*)(np);
                n1 = *(const float4*)(np + HW);
                n2 = *(const float4*)(np + 2 * HW);
            }
            if (lane < 32) hist[wv][lane] = 0;
            asm volatile("s_waitcnt lgkmcnt(0)" ::: "memory");   // zero visible wave-wide
            float g[4] = { (c0.x + c1.x + c2.x) / 3.0f, (c0.y + c1.y + c2.y) / 3.0f,
                           (c0.z + c1.z + c2.z) / 3.0f, (c0.w + c1.w + c2.w) / 3.0f };
#pragma unroll
            for (int j = 0; j < 4; ++j) {
                int bin = (int)(g[j] * 31.0f);
                bin = bin < 0 ? 0 : (bin > 31 ? 31 : bin);
                atomicAdd(&hist[wv][bin], 1);
            }
            asm volatile("s_waitcnt lgkmcnt(0)" ::: "memory");   // atomics done
            float t = 0.0f;
            if (lane < 32) {
                float prb = (float)hist[wv][lane] * (1.0f / 256.0f);
                t = -prb * log2f(prb + 1e-10f);
            }
#pragma unroll
            for (int off = 32; off; off >>= 1) t += __shfl_xor(t, off);
            if (lane == 0) ent[rowBase + pp] = t * (1.0f / 5.0f);  // / log2(32)
            c0 = n0; c1 = n1; c2 = n2;
        }
    }

    // ---- stage tile 0 into LDS (prologue loads have landed by now) ----
    if (tid < 256) *(s16x8*)(As + sA1) = cvt8(a1lo, a1hi);
#pragma unroll
    for (int i = 0; i < 8; ++i)
        *(s16x8*)(Bs + sB + i * (48 * 64)) = breg[i];
    __syncthreads();

    // ---- main K-loop: issue loads(kt+1) -> MFMA(kt) -> barrier -> ds_write ----
    f32x4 acc[2][4] = {};
    for (int kt = 0; kt < 12; ++kt) {
        if (kt < 11) {
            const int kn = kt + 1;
            if (tid < 256) {
                const float* pa = pA1 + (kn >> 2) * HW + (kn & 3) * (4 * 224);
                a1lo = *(const float4*)(pa);
                a1hi = *(const float4*)(pa + 4);
            }
#pragma unroll
            for (int i = 0; i < 8; ++i)
                breg[i] = *(const s16x8*)(pB0 + (size_t)i * (48 * KDIM) + kn * 64);
        }
#pragma unroll
        for (int ks = 0; ks < 2; ++ks) {
            const int sw = (ks * 4 + quad) ^ (cl & 7);
            s16x8 a_frag[2], b_frag[4];
#pragma unroll
            for (int i = 0; i < 2; ++i)
                a_frag[i] = *(const s16x8*)(As + (i * 16 + cl) * 64 + sw * 8);
#pragma unroll
            for (int j = 0; j < 4; ++j)
                b_frag[j] = *(const s16x8*)(Bs + (wv * 64 + j * 16 + cl) * 64 + sw * 8);
#pragma unroll
            for (int i = 0; i < 2; ++i)
#pragma unroll
                for (int j = 0; j < 4; ++j)
                    acc[i][j] = __builtin_amdgcn_mfma_f32_16x16x32_bf16(
                        a_frag[i], b_frag[j], acc[i][j], 0, 0, 0);
        }
        __syncthreads();                       // all waves done reading tile kt
        if (kt < 11) {
            if (tid < 256) *(s16x8*)(As + sA1) = cvt8(a1lo, a1hi);
#pragma unroll
            for (int i = 0; i < 8; ++i)
                *(s16x8*)(Bs + sB + i * (48 * 64)) = breg[i];
        }
        __syncthreads();                       // tile kt+1 ready
    }

    // ---- epilogue: bias + LayerNorm(384) + write ----
    float bv[4], gv[4], btv[4];
#pragma unroll
    for (int j = 0; j < 4; ++j) {
        int col = wv * 64 + j * 16 + cl;
        bv[j] = bias[col]; gv[j] = gamma[col]; btv[j] = beta[col];
    }

#pragma unroll
    for (int i = 0; i < 2; ++i) {
#pragma unroll
        for (int r = 0; r < 4; ++r) {
            float s1 = 0.0f, s2 = 0.0f;
#pragma unroll
            for (int j = 0; j < 4; ++j) {
                float v = acc[i][j][r] + bv[j];
                s1 += v; s2 += v * v;
            }
#pragma unroll
            for (int off = 1; off < 16; off <<= 1) {
                s1 += __shfl_xor(s1, off);
                s2 += __shfl_xor(s2, off);
            }
            if (cl == 0) {
                int row = i * 16 + quad * 4 + r;
                atomicAdd(&sred[row], s1);
                atomicAdd(&sred2[row], s2);
            }
        }
    }
    __syncthreads();
    if (tid < 32) {
        float mu  = sred[tid] * (1.0f / (float)DDIM);
        float var = sred2[tid] * (1.0f / (float)DDIM) - mu * mu;
        smean[tid] = mu;
        srstd[tid] = rsqrtf(var + 1e-5f);
    }
    __syncthreads();

#pragma unroll
    for (int i = 0; i < 2; ++i) {
#pragma unroll
        for (int r = 0; r < 4; ++r) {
            int row = i * 16 + quad * 4 + r;
            float mu = smean[row], rs = srstd[row];
            float* crow = C + (size_t)(rowBase + row) * DDIM;
#pragma unroll
            for (int j = 0; j < 4; ++j)
                crow[wv * 64 + j * 16 + cl] = (acc[i][j][r] + bv[j] - mu) * rs * gv[j] + btv[j];
        }
    }
}

extern "C" void kernel_launch(void* const* d_in, const int* in_sizes, int n_in,
                              void* d_out, int out_size, void* d_ws, size_t ws_size,
                              hipStream_t stream) {
    const float* img = (const float*)d_in[0];
    const float* pw  = (const float*)d_in[1];
    const float* pb  = (const float*)d_in[2];
    const float* gam = (const float*)d_in[3];
    const float* bet = (const float*)d_in[4];
    float* out = (float*)d_out;

    unsigned short* Wbf = (unsigned short*)d_ws;          // 384*768*2 = 589824 B
    float* ent = out + (size_t)M_ROWS * DDIM;             // entropy after x

    hipLaunchKernelGGL(wcast_kernel, dim3(288), dim3(256), 0, stream, pw, Wbf);
    hipLaunchKernelGGL(fused_kernel, dim3(392), dim3(384), 0, stream,
                       img, Wbf, pb, gam, bet, out, ent);
}